// Round 6
// baseline (355.219 us; speedup 1.0000x reference)
//
#include <hip/hip_runtime.h>
#include <math.h>

// ConvSlimCapsule3D fused, round 6: d-march pipeline.
// Block = (b, h, wseg, dgroup) marches 8 d values. LDS: 3-slot rolling ring of
// z-planes (slot = 3 y-rows x 18 j x 128 ch f16, swizzled) + zero row + votes.
// Per d: barrier-free GEMM (M=128,N=128,K=448, mfma_f32_16x16x32_f16) -> dump
// prefetched next z-plane (regs->dead slot) -> issue next prefetch -> votes ->
// routing. Staging is off the critical path; B coalesced + L1/L2-resident.

typedef _Float16 half8 __attribute__((ext_vector_type(8)));
typedef float f32x4 __attribute__((ext_vector_type(4)));

// prep: cw (n=128, ca=16, tap=27) f32 -> whB[c 0..13][q 0..3][n 0..127][e 0..7]
// f16, k = q*8+e = tp*16+ca, tap = 2c+tp, tap>=27 -> 0 (matches A zero row)
__global__ __launch_bounds__(256) void prep_weights(const float* __restrict__ cw,
                                                    _Float16* __restrict__ whB) {
    const int idx = blockIdx.x * 256 + threadIdx.x;   // 57344
    const int e = idx & 7, n = (idx >> 3) & 127;
    const int q = (idx >> 10) & 3, c = idx >> 12;
    const int k = q * 8 + e, tp = k >> 4, ca = k & 15, tap = 2 * c + tp;
    float v = (tap < 27) ? cw[n * 432 + ca * 27 + tap] : 0.0f;
    whB[idx] = (_Float16)v;
}

__device__ __forceinline__ int s3(int v) {            // (v in 0..6) mod 3
    v = (v >= 3) ? v - 3 : v;
    return (v >= 3) ? v - 3 : v;
}

__global__ __launch_bounds__(512, 4) void caps_kernel(
    const float* __restrict__ x,      // (2,8,16,32,32,32) f32
    const _Float16* __restrict__ whB, // (14,4,128,8) f16
    const float* __restrict__ cb,     // (128,)
    const float* __restrict__ bias,   // (8,16)
    float* __restrict__ out)          // (2,8,16,32,32,32) f32
{
    __shared__ half8 smemv[4944];     // 79104 B = ring 41472 + zero 4608 + votes 33024
    char* smem = (char*)smemv;
    _Float16* Vh = (_Float16*)(smem + 46080);
    float* RT = (float*)(smem + 46080);          // overlays votes after B3
    float* LG = (float*)(smem + 46080) + 1152;

    const int t    = threadIdx.x;     // 0..511
    const int gid  = blockIdx.x;      // 512
    const int wseg = gid & 1;
    const int h    = (gid >> 1) & 31;
    const int dg   = (gid >> 6) & 3;
    const int b    = (gid >> 8) & 1;
    const int w0g  = wseg << 4;
    const int d0   = dg << 3;

    const float* xb = x + (size_t)b * 4194304;

    // ---- per-thread staging geometry (fixed for all planes) ----
    int gBase[3], segI[3], dyI[3], chI[3];
    bool yvI[3];
    #pragma unroll
    for (int k = 0; k < 3; k++) {
        const int tid = t + k * 512;          // 0..1535
        const int row = tid >> 2;             // 0..383
        segI[k] = tid & 3;
        dyI[k]  = row >> 7;
        chI[k]  = row & 127;
        const int y = h + dyI[k] - 1;
        yvI[k] = ((unsigned)y < 32u);
        gBase[k] = chI[k] * 32768 + y * 32 + w0g + segI[k] * 4;
    }
    const bool edgeAct = (t < 384);
    const int dyE = (t >> 7) & 3, chE = t & 127;
    const int yE = h + dyE - 1;
    const bool yvE = edgeAct && ((unsigned)yE < 32u);
    const int wsc = (w0g == 0) ? 16 : 15;
    const int jsc = (w0g == 0) ? 17 : 0;
    const int jz  = (w0g == 0) ? 0 : 17;
    const int gBaseE = chE * 32768 + yE * 32 + wsc;

    f32x4 pv[3];
    float pe;

    auto loadPlane = [&](int zz) {
        const bool zv = ((unsigned)zz < 32u);
        #pragma unroll
        for (int k = 0; k < 3; k++) {
            pv[k] = (f32x4)0.f;
            if (zv && yvI[k]) pv[k] = *(const f32x4*)(xb + gBase[k] + zz * 1024);
        }
        pe = 0.f;
        if (zv && yvE) pe = xb[gBaseE + zz * 1024];
    };
    auto dumpPlane = [&](int slot) {
        const int sb = slot * 13824;
        #pragma unroll
        for (int k = 0; k < 3; k++) {
            #pragma unroll
            for (int e = 0; e < 4; e++) {
                const int j = segI[k] * 4 + 1 + e;
                *(_Float16*)(smem + sb + dyI[k] * 4608 + j * 256
                             + (((chI[k] >> 3) ^ (j & 15)) << 4)
                             + ((chI[k] & 7) << 1)) = (_Float16)pv[k][e];
            }
        }
        if (edgeAct) {
            *(_Float16*)(smem + sb + dyE * 4608 + jsc * 256
                         + (((chE >> 3) ^ (jsc & 15)) << 4) + ((chE & 7) << 1)) = (_Float16)pe;
            *(_Float16*)(smem + sb + dyE * 4608 + jz * 256
                         + (((chE >> 3) ^ (jz & 15)) << 4) + ((chE & 7) << 1)) = (_Float16)0.f;
        }
    };

    const int dm0 = d0 % 3;

    // ---- fill: planes z = d0-1..d0+1, zero-row, prefetch z = d0+2 ----
    #pragma unroll 1
    for (int p = 0; p < 3; p++) {
        loadPlane(d0 - 1 + p);
        dumpPlane(s3(dm0 + 2 + p));
    }
    for (int i2 = t; i2 < 1152; i2 += 512) ((float*)(smem + 41472))[i2] = 0.f;
    loadPlane(d0 + 2);
    __syncthreads();

    // ---- GEMM geometry ----
    const int wid = t >> 6, lane = t & 63;
    const int q = lane >> 4, r = lane & 15;
    const int wy = wid >> 2, wx = wid & 3;    // 2 M-groups x 4 N-groups
    const int qlow = q & 1, tphase = q >> 1;

    int geo[14];   // dz | dy<<2 | dx<<4 | pad<<6
    #pragma unroll
    for (int c = 0; c < 14; c++) {
        const int tap = 2 * c + tphase;
        const int dz = tap / 9, r9 = tap - dz * 9;
        const int dy = r9 / 3, dx = r9 - dy * 3;
        geo[c] = (tap >= 27) ? 64 : (dz | (dy << 2) | (dx << 4));
    }
    int uA[4];
    #pragma unroll
    for (int mt = 0; mt < 4; mt++) uA[mt] = (wy * 4 + mt) * 2 + qlow;
    const _Float16* bpt = whB + (q * 128 + wx * 32 + r) * 8;

    // ---- routing geometry (hoisted) ----
    const int p2 = t >> 2, qd = t & 3;
    const int vv = p2 & 15, oo = p2 >> 4;
    float cbv[2], bl[4];
    #pragma unroll
    for (int nt = 0; nt < 2; nt++) cbv[nt] = cb[wx * 32 + nt * 16 + r];
    #pragma unroll
    for (int a = 0; a < 4; a++) bl[a] = bias[oo * 16 + qd * 4 + a];

    int dmC = dm0;

    #pragma unroll 1
    for (int d = 0; d < 8; ++d) {
        // ================= GEMM d (reads ring slots, no barriers) ==============
        f32x4 acc[4][2];
        #pragma unroll
        for (int i = 0; i < 4; i++)
            #pragma unroll
            for (int j = 0; j < 2; j++) acc[i][j] = (f32x4)0.f;

        half8 bf[2][2];
        #pragma unroll
        for (int nt = 0; nt < 2; nt++) bf[0][nt] = *(const half8*)(bpt + nt * 128);

        #pragma unroll
        for (int c = 0; c < 14; c++) {
            const int cur = c & 1;
            if (c < 13) {
                #pragma unroll
                for (int nt = 0; nt < 2; nt++)
                    bf[cur ^ 1][nt] = *(const half8*)(bpt + (c + 1) * 4096 + nt * 128);
            }
            const int g = geo[c];
            int sx = dmC + (g & 3) + 2;
            sx = (sx >= 3) ? sx - 3 : sx;
            sx = (sx >= 3) ? sx - 3 : sx;
            int rb = sx * 13824 + ((g >> 2) & 3) * 4608;
            rb = (g & 64) ? 41472 : rb;
            const int jw = r + ((g >> 4) & 3);
            const int rowb = rb + jw * 256;
            const int js = jw & 15;
            half8 af[4];
            #pragma unroll
            for (int mt = 0; mt < 4; mt++)
                af[mt] = *(const half8*)(smem + rowb + ((uA[mt] ^ js) << 4));
            #pragma unroll
            for (int mt = 0; mt < 4; mt++)
                #pragma unroll
                for (int nt = 0; nt < 2; nt++)
                    acc[mt][nt] = __builtin_amdgcn_mfma_f32_16x16x32_f16(
                        af[mt], bf[cur][nt], acc[mt][nt], 0, 0, 0);
        }
        __syncthreads();   // B1: all slab reads for d done

        // ---- dump prefetched plane z = d0+d+2 into dead slot, prefetch next ----
        if (d < 7) dumpPlane(s3(dmC + 2));
        if (d < 6) loadPlane(d0 + d + 3);

        // ---- votes epilogue: acc + conv bias -> Vh[v][i][n] f16 ----
        #pragma unroll
        for (int mt = 0; mt < 4; mt++) {
            #pragma unroll
            for (int nt = 0; nt < 2; nt++) {
                const int n = wx * 32 + nt * 16 + r;
                #pragma unroll
                for (int reg = 0; reg < 4; reg++) {
                    const int v = q * 4 + reg;       // C/D row = q*4+reg (verified)
                    const int i = wy * 4 + mt;
                    Vh[v * 1032 + i * 128 + n] = (_Float16)(acc[mt][nt][reg] + cbv[nt]);
                }
            }
        }
        __syncthreads();   // B2: votes + dumped plane visible

        // ================= routing: 128 (v,o) pairs x 4 atom-quarters ==========
        float vf[8][4];
        #pragma unroll
        for (int i = 0; i < 8; i++) {
            const half8* hp = (const half8*)&Vh[vv * 1032 + i * 128 + oo * 16 + qd * 4];
            const _Float16* hs = (const _Float16*)hp;
            #pragma unroll
            for (int a = 0; a < 4; a++) vf[i][a] = (float)hs[a];
        }
        __syncthreads();   // B3: vote reads done -> RT/LG may overlay

        float vn[8];
        #pragma unroll
        for (int i = 0; i < 8; i++) {
            float s = 0.f;
            #pragma unroll
            for (int a = 0; a < 4; a++) s = fmaf(vf[i][a], vf[i][a], s);
            s += __shfl_xor(s, 1);
            s += __shfl_xor(s, 2);
            vn[i] = sqrtf(s);
        }

        float rt[8], pre[4];
        float lgr[8];
        #pragma unroll
        for (int i = 0; i < 8; i++) { rt[i] = 0.125f; lgr[i] = 0.f; }

        for (int it = 0; it < 3; it++) {
            #pragma unroll
            for (int a = 0; a < 4; a++) {
                float s = bl[a];
                #pragma unroll
                for (int i = 0; i < 8; i++) s = fmaf(rt[i], vf[i][a], s);
                pre[a] = s;
            }
            if (it == 2) break;

            float s2 = 0.f;
            #pragma unroll
            for (int a = 0; a < 4; a++) s2 = fmaf(pre[a], pre[a], s2);
            s2 += __shfl_xor(s2, 1);
            s2 += __shfl_xor(s2, 2);
            const float pn = sqrtf(s2);

            #pragma unroll
            for (int i = 0; i < 8; i++) {
                float dp = 0.f;
                #pragma unroll
                for (int a = 0; a < 4; a++) dp = fmaf(pre[a], vf[i][a], dp);
                dp += __shfl_xor(dp, 1);
                dp += __shfl_xor(dp, 2);
                lgr[i] += dp / fmaxf(pn * vn[i], 1e-8f);
            }
            if (qd == 0) {
                #pragma unroll
                for (int i = 0; i < 8; i++) LG[vv * 72 + i * 8 + oo] = lgr[i];
            }
            __syncthreads();

            {
                float ex[2], ps = 0.f;
                #pragma unroll
                for (int k = 0; k < 2; k++) {
                    ex[k] = __expf(LG[vv * 72 + oo * 8 + qd * 2 + k]);
                    ps += ex[k];
                }
                ps += __shfl_xor(ps, 1);
                ps += __shfl_xor(ps, 2);
                const float rs = 1.f / ps;
                #pragma unroll
                for (int k = 0; k < 2; k++)
                    RT[vv * 72 + oo * 8 + qd * 2 + k] = ex[k] * rs;
            }
            __syncthreads();

            #pragma unroll
            for (int i = 0; i < 8; i++) rt[i] = RT[vv * 72 + i * 8 + oo];
        }

        // ---- squash + store ----
        float s2 = 0.f;
        #pragma unroll
        for (int a = 0; a < 4; a++) s2 = fmaf(pre[a], pre[a], s2);
        s2 += __shfl_xor(s2, 1);
        s2 += __shfl_xor(s2, 2);
        const float nn = sqrtf(s2);
        const float scale = (s2 / (1.f + s2)) / (nn + 1e-12f);
        const size_t sp = (size_t)(d0 + d) * 1024 + h * 32 + w0g + vv;
        #pragma unroll
        for (int a = 0; a < 4; a++)
            out[((size_t)((b * 8 + oo) * 16 + qd * 4 + a)) * 32768 + sp] = pre[a] * scale;

        dmC = (dmC == 2) ? 0 : dmC + 1;
    }
}

extern "C" void kernel_launch(void* const* d_in, const int* in_sizes, int n_in,
                              void* d_out, int out_size, void* d_ws, size_t ws_size,
                              hipStream_t stream) {
    const float* x    = (const float*)d_in[0];
    const float* cw   = (const float*)d_in[1];
    const float* cb   = (const float*)d_in[2];
    const float* bias = (const float*)d_in[3];
    float* out = (float*)d_out;
    _Float16* whB = (_Float16*)d_ws;   // 57344 * 2 = 114688 B

    hipLaunchKernelGGL(prep_weights, dim3(224), dim3(256), 0, stream, cw, whB);
    hipLaunchKernelGGL(caps_kernel, dim3(512), dim3(512), 0, stream,
                       x, whB, cb, bias, out);
}

// Round 7
// 337.683 us; speedup vs baseline: 1.0519x; 1.0519x over previous
//
#include <hip/hip_runtime.h>
#include <math.h>

// ConvSlimCapsule3D fused, round 7: d-march pipeline, de-scratched (no lambdas).
// Block = (b, h, wseg, dgroup) marches 8 d values. LDS: 3-slot rolling ring of
// z-planes (slot = 3 y-rows x 18 j x 128 ch f16, swizzled) + zero row + votes.
// Per d: barrier-free GEMM (M=128,N=128,K=448, mfma_f32_16x16x32_f16) -> dump
// register-prefetched next z-plane into dead slot -> prefetch next -> votes ->
// routing. Staging state: 3 named f32x4 + 4 slot-invariant LDS offsets.

typedef _Float16 half8 __attribute__((ext_vector_type(8)));
typedef _Float16 half4 __attribute__((ext_vector_type(4)));
typedef float f32x4 __attribute__((ext_vector_type(4)));

// prep: cw (n=128, ca=16, tap=27) f32 -> whB[c 0..13][q 0..3][n 0..127][e 0..7]
// f16, k = q*8+e = tp*16+ca, tap = 2c+tp, tap>=27 -> 0 (matches A zero row)
__global__ __launch_bounds__(256) void prep_weights(const float* __restrict__ cw,
                                                    _Float16* __restrict__ whB) {
    const int idx = blockIdx.x * 256 + threadIdx.x;   // 57344
    const int e = idx & 7, n = (idx >> 3) & 127;
    const int q = (idx >> 10) & 3, c = idx >> 12;
    const int k = q * 8 + e, tp = k >> 4, ca = k & 15, tap = 2 * c + tp;
    float v = (tap < 27) ? cw[n * 432 + ca * 27 + tap] : 0.0f;
    whB[idx] = (_Float16)v;
}

__device__ __forceinline__ int s3(int v) {            // (v in 0..6) mod 3
    v = (v >= 3) ? v - 3 : v;
    return (v >= 3) ? v - 3 : v;
}

// load planes z into pv0..pv2 / pe (registers only)
#define LOADPLANE(zz_) do {                                                    \
    const int zz = (zz_);                                                      \
    const bool zv = ((unsigned)zz < 32u);                                      \
    const int zo = zz << 10;                                                   \
    pv0 = (f32x4)0.f; pv1 = (f32x4)0.f; pv2 = (f32x4)0.f; pe = 0.f;            \
    if (zv) {                                                                  \
        if (yv0) pv0 = *(const f32x4*)(xb + gBase + zo);                       \
        if (yv1) pv1 = *(const f32x4*)(xb + gBase + 32 + zo);                  \
        if (yv2) pv2 = *(const f32x4*)(xb + gBase + 64 + zo);                  \
        if (yvE) pe  = xb[gBaseE + zo];                                        \
    }                                                                          \
} while (0)

// dump pv0..pv2 / pe into ring slot (12 ds_write_b16 + 2 edge)
#define DUMPPLANE(slot_) do {                                                  \
    const int sb = (slot_) * 13824;                                            \
    _Pragma("unroll")                                                          \
    for (int e = 0; e < 4; e++) {                                              \
        *(_Float16*)(smem + sb +        offJ[e]) = (_Float16)pv0[e];           \
        *(_Float16*)(smem + sb + 4608 + offJ[e]) = (_Float16)pv1[e];           \
        *(_Float16*)(smem + sb + 9216 + offJ[e]) = (_Float16)pv2[e];           \
    }                                                                          \
    if (edgeAct) {                                                             \
        *(_Float16*)(smem + sb + offE1) = (_Float16)pe;                        \
        *(_Float16*)(smem + sb + offE0) = (_Float16)0.f;                       \
    }                                                                          \
} while (0)

__global__ __launch_bounds__(512, 4) void caps_kernel(
    const float* __restrict__ x,      // (2,8,16,32,32,32) f32
    const _Float16* __restrict__ whB, // (14,4,128,8) f16
    const float* __restrict__ cb,     // (128,)
    const float* __restrict__ bias,   // (8,16)
    float* __restrict__ out)          // (2,8,16,32,32,32) f32
{
    __shared__ half8 smemv[4944];     // 79104 B = ring 41472 + zero 4608 + votes 33024
    char* smem = (char*)smemv;
    _Float16* Vh = (_Float16*)(smem + 46080);
    float* RT = (float*)(smem + 46080);          // overlays votes after B3
    float* LG = (float*)(smem + 46080) + 1152;

    const int t    = threadIdx.x;     // 0..511
    const int gid  = blockIdx.x;      // 512
    const int wseg = gid & 1;
    const int h    = (gid >> 1) & 31;
    const int dg   = (gid >> 6) & 3;
    const int b    = (gid >> 8) & 1;
    const int w0g  = wseg << 4;
    const int d0   = dg << 3;

    const float* xb = x + (size_t)b * 4194304;

    // ---- staging geometry: thread handles (ch = t>>2, seg = t&3) at dy = 0,1,2 ----
    const int ch  = t >> 2;
    const int seg = t & 3;
    const bool yv0 = (h >= 1), yv1 = true, yv2 = (h <= 30);
    const int gBase = ch * 32768 + (h - 1) * 32 + w0g + seg * 4;  // float units
    int offJ[4];
    #pragma unroll
    for (int e = 0; e < 4; e++) {
        const int j = seg * 4 + 1 + e;           // 1..16
        offJ[e] = j * 256 + (((ch >> 3) ^ (j & 15)) << 4) + ((ch & 7) << 1);
    }
    // edge task: threads 0..383 -> (dyE = t>>7, chE = t&127)
    const bool edgeAct = (t < 384);
    const int dyE = (t >> 7) & 3, chE = t & 127;
    const int yE = h + dyE - 1;
    const bool yvE = edgeAct && ((unsigned)yE < 32u);
    const int wsc = (w0g == 0) ? 16 : 15;
    const int jsc = (w0g == 0) ? 17 : 0;
    const int jz  = (w0g == 0) ? 0 : 17;
    const int gBaseE = chE * 32768 + yE * 32 + wsc;
    const int offE1 = dyE * 4608 + jsc * 256 + (((chE >> 3) ^ (jsc & 15)) << 4)
                      + ((chE & 7) << 1);
    const int offE0 = dyE * 4608 + jz * 256 + (((chE >> 3) ^ (jz & 15)) << 4)
                      + ((chE & 7) << 1);

    f32x4 pv0, pv1, pv2;
    float pe;

    const int dm0 = d0 % 3;

    // ---- fill: planes z = d0-1, d0, d0+1 -> slots s3(dm0+2), dm0, s3(dm0+1) ----
    LOADPLANE(d0 - 1);  DUMPPLANE(s3(dm0 + 2));
    LOADPLANE(d0);      DUMPPLANE(dm0);
    LOADPLANE(d0 + 1);  DUMPPLANE(s3(dm0 + 1));
    for (int i2 = t; i2 < 1152; i2 += 512) ((float*)(smem + 41472))[i2] = 0.f;
    LOADPLANE(d0 + 2);                        // prefetch for d=0's dump
    __syncthreads();

    // ---- GEMM geometry ----
    const int wid = t >> 6, lane = t & 63;
    const int q = lane >> 4, r = lane & 15;
    const int wy = wid >> 2, wx = wid & 3;    // 2 M-groups x 4 N-groups
    const int qlow = q & 1, tphase = q >> 1;

    int geo[14];   // dz | dy<<2 | dx<<4 | pad<<6
    #pragma unroll
    for (int c = 0; c < 14; c++) {
        const int tap = 2 * c + tphase;
        const int dz = tap / 9, r9 = tap - dz * 9;
        const int dy = r9 / 3, dx = r9 - dy * 3;
        geo[c] = (tap >= 27) ? 64 : (dz | (dy << 2) | (dx << 4));
    }
    int uA[4];
    #pragma unroll
    for (int mt = 0; mt < 4; mt++) uA[mt] = (wy * 4 + mt) * 2 + qlow;
    const _Float16* bpt = whB + (q * 128 + wx * 32 + r) * 8;

    // ---- routing geometry (hoisted) ----
    const int p2 = t >> 2, qd = t & 3;
    const int vv = p2 & 15, oo = p2 >> 4;
    float cbv[2], bl[4];
    #pragma unroll
    for (int nt = 0; nt < 2; nt++) cbv[nt] = cb[wx * 32 + nt * 16 + r];
    #pragma unroll
    for (int a = 0; a < 4; a++) bl[a] = bias[oo * 16 + qd * 4 + a];

    int dmC = dm0;

    #pragma unroll 1
    for (int d = 0; d < 8; ++d) {
        // ================= GEMM d (reads ring slots, no barriers) ==============
        f32x4 acc[4][2];
        #pragma unroll
        for (int i = 0; i < 4; i++)
            #pragma unroll
            for (int j = 0; j < 2; j++) acc[i][j] = (f32x4)0.f;

        half8 bf[2][2];
        #pragma unroll
        for (int nt = 0; nt < 2; nt++) bf[0][nt] = *(const half8*)(bpt + nt * 128);

        #pragma unroll
        for (int c = 0; c < 14; c++) {
            const int cur = c & 1;
            if (c < 13) {
                #pragma unroll
                for (int nt = 0; nt < 2; nt++)
                    bf[cur ^ 1][nt] = *(const half8*)(bpt + (c + 1) * 4096 + nt * 128);
            }
            const int g = geo[c];
            int sx = dmC + (g & 3) + 2;
            sx = (sx >= 3) ? sx - 3 : sx;
            sx = (sx >= 3) ? sx - 3 : sx;
            int rb = sx * 13824 + ((g >> 2) & 3) * 4608;
            rb = (g & 64) ? 41472 : rb;
            const int jw = r + ((g >> 4) & 3);
            const int rowb = rb + jw * 256;
            const int js = jw & 15;
            half8 af[4];
            #pragma unroll
            for (int mt = 0; mt < 4; mt++)
                af[mt] = *(const half8*)(smem + rowb + ((uA[mt] ^ js) << 4));
            #pragma unroll
            for (int mt = 0; mt < 4; mt++)
                #pragma unroll
                for (int nt = 0; nt < 2; nt++)
                    acc[mt][nt] = __builtin_amdgcn_mfma_f32_16x16x32_f16(
                        af[mt], bf[cur][nt], acc[mt][nt], 0, 0, 0);
        }
        __syncthreads();   // B1: all slab reads for d done

        // ---- dump prefetched plane z = d0+d+2 into dead slot, prefetch next ----
        if (d < 7) DUMPPLANE(s3(dmC + 2));
        if (d < 6) LOADPLANE(d0 + d + 3);

        // ---- votes epilogue: acc + conv bias -> Vh[v][i][n] f16 ----
        #pragma unroll
        for (int mt = 0; mt < 4; mt++) {
            #pragma unroll
            for (int nt = 0; nt < 2; nt++) {
                const int n = wx * 32 + nt * 16 + r;
                #pragma unroll
                for (int reg = 0; reg < 4; reg++) {
                    const int v = q * 4 + reg;       // C/D row = q*4+reg (verified)
                    const int i = wy * 4 + mt;
                    Vh[v * 1032 + i * 128 + n] = (_Float16)(acc[mt][nt][reg] + cbv[nt]);
                }
            }
        }
        __syncthreads();   // B2: votes + dumped plane visible

        // ================= routing: 128 (v,o) pairs x 4 atom-quarters ==========
        float vf[8][4];
        #pragma unroll
        for (int i = 0; i < 8; i++) {
            const half4 hv = *(const half4*)&Vh[vv * 1032 + i * 128 + oo * 16 + qd * 4];
            #pragma unroll
            for (int a = 0; a < 4; a++) vf[i][a] = (float)hv[a];
        }
        __syncthreads();   // B3: vote reads done -> RT/LG may overlay

        float vn[8];
        #pragma unroll
        for (int i = 0; i < 8; i++) {
            float s = 0.f;
            #pragma unroll
            for (int a = 0; a < 4; a++) s = fmaf(vf[i][a], vf[i][a], s);
            s += __shfl_xor(s, 1);
            s += __shfl_xor(s, 2);
            vn[i] = sqrtf(s);
        }

        float rt[8], pre[4];
        float lgr[8];
        #pragma unroll
        for (int i = 0; i < 8; i++) { rt[i] = 0.125f; lgr[i] = 0.f; }

        for (int it = 0; it < 3; it++) {
            #pragma unroll
            for (int a = 0; a < 4; a++) {
                float s = bl[a];
                #pragma unroll
                for (int i = 0; i < 8; i++) s = fmaf(rt[i], vf[i][a], s);
                pre[a] = s;
            }
            if (it == 2) break;

            float s2 = 0.f;
            #pragma unroll
            for (int a = 0; a < 4; a++) s2 = fmaf(pre[a], pre[a], s2);
            s2 += __shfl_xor(s2, 1);
            s2 += __shfl_xor(s2, 2);
            const float pn = sqrtf(s2);

            #pragma unroll
            for (int i = 0; i < 8; i++) {
                float dp = 0.f;
                #pragma unroll
                for (int a = 0; a < 4; a++) dp = fmaf(pre[a], vf[i][a], dp);
                dp += __shfl_xor(dp, 1);
                dp += __shfl_xor(dp, 2);
                lgr[i] += dp / fmaxf(pn * vn[i], 1e-8f);
            }
            if (qd == 0) {
                #pragma unroll
                for (int i = 0; i < 8; i++) LG[vv * 72 + i * 8 + oo] = lgr[i];
            }
            __syncthreads();

            {
                float ex[2], ps = 0.f;
                #pragma unroll
                for (int k = 0; k < 2; k++) {
                    ex[k] = __expf(LG[vv * 72 + oo * 8 + qd * 2 + k]);
                    ps += ex[k];
                }
                ps += __shfl_xor(ps, 1);
                ps += __shfl_xor(ps, 2);
                const float rs = 1.f / ps;
                #pragma unroll
                for (int k = 0; k < 2; k++)
                    RT[vv * 72 + oo * 8 + qd * 2 + k] = ex[k] * rs;
            }
            __syncthreads();

            #pragma unroll
            for (int i = 0; i < 8; i++) rt[i] = RT[vv * 72 + i * 8 + oo];
        }

        // ---- squash + store ----
        float s2 = 0.f;
        #pragma unroll
        for (int a = 0; a < 4; a++) s2 = fmaf(pre[a], pre[a], s2);
        s2 += __shfl_xor(s2, 1);
        s2 += __shfl_xor(s2, 2);
        const float nn = sqrtf(s2);
        const float scale = (s2 / (1.f + s2)) / (nn + 1e-12f);
        const size_t sp = (size_t)(d0 + d) * 1024 + h * 32 + w0g + vv;
        #pragma unroll
        for (int a = 0; a < 4; a++)
            out[((size_t)((b * 8 + oo) * 16 + qd * 4 + a)) * 32768 + sp] = pre[a] * scale;

        dmC = (dmC == 2) ? 0 : dmC + 1;
    }
}

extern "C" void kernel_launch(void* const* d_in, const int* in_sizes, int n_in,
                              void* d_out, int out_size, void* d_ws, size_t ws_size,
                              hipStream_t stream) {
    const float* x    = (const float*)d_in[0];
    const float* cw   = (const float*)d_in[1];
    const float* cb   = (const float*)d_in[2];
    const float* bias = (const float*)d_in[3];
    float* out = (float*)d_out;
    _Float16* whB = (_Float16*)d_ws;   // 57344 * 2 = 114688 B

    hipLaunchKernelGGL(prep_weights, dim3(224), dim3(256), 0, stream, cw, whB);
    hipLaunchKernelGGL(caps_kernel, dim3(512), dim3(512), 0, stream,
                       x, whB, cb, bias, out);
}

// Round 8
// 337.307 us; speedup vs baseline: 1.0531x; 1.0011x over previous
//
#include <hip/hip_runtime.h>
#include <math.h>

// ConvSlimCapsule3D fused, round 8: round-7 d-march with the register allocator
// un-starved. Key fix: __launch_bounds__(512,4) set amdgpu-waves-per-eu=[4,inf)
// -> backend chased 8 waves/EU, capping VGPRs at 64 and spilling ~900B/thread to
// scratch (722 MB FETCH / 220 MB WRITE in r6/r7). amdgpu_waves_per_eu(4,4) pins
// the target: full 128-VGPR budget, no spill (LDS caps us at 2 blocks/CU anyway).

typedef _Float16 half8 __attribute__((ext_vector_type(8)));
typedef _Float16 half4 __attribute__((ext_vector_type(4)));
typedef float f32x4 __attribute__((ext_vector_type(4)));

// prep: cw (n=128, ca=16, tap=27) f32 -> whB[c 0..13][q 0..3][n 0..127][e 0..7]
// f16, k = q*8+e = tp*16+ca, tap = 2c+tp, tap>=27 -> 0 (matches A zero row)
__global__ __launch_bounds__(256) void prep_weights(const float* __restrict__ cw,
                                                    _Float16* __restrict__ whB) {
    const int idx = blockIdx.x * 256 + threadIdx.x;   // 57344
    const int e = idx & 7, n = (idx >> 3) & 127;
    const int q = (idx >> 10) & 3, c = idx >> 12;
    const int k = q * 8 + e, tp = k >> 4, ca = k & 15, tap = 2 * c + tp;
    float v = (tap < 27) ? cw[n * 432 + ca * 27 + tap] : 0.0f;
    whB[idx] = (_Float16)v;
}

__device__ __forceinline__ int s3(int v) {            // (v in 0..6) mod 3
    v = (v >= 3) ? v - 3 : v;
    return (v >= 3) ? v - 3 : v;
}

// load planes z into pv0..pv2 / pe (registers only)
#define LOADPLANE(zz_) do {                                                    \
    const int zz = (zz_);                                                      \
    const bool zv = ((unsigned)zz < 32u);                                      \
    const int zo = zz << 10;                                                   \
    pv0 = (f32x4)0.f; pv1 = (f32x4)0.f; pv2 = (f32x4)0.f; pe = 0.f;            \
    if (zv) {                                                                  \
        if (yv0) pv0 = *(const f32x4*)(xb + gBase + zo);                       \
        if (yv1) pv1 = *(const f32x4*)(xb + gBase + 32 + zo);                  \
        if (yv2) pv2 = *(const f32x4*)(xb + gBase + 64 + zo);                  \
        if (yvE) pe  = xb[gBaseE + zo];                                        \
    }                                                                          \
} while (0)

// dump pv0..pv2 / pe into ring slot (12 ds_write_b16 + 2 edge)
#define DUMPPLANE(slot_) do {                                                  \
    const int sb = (slot_) * 13824;                                            \
    _Pragma("unroll")                                                          \
    for (int e = 0; e < 4; e++) {                                              \
        *(_Float16*)(smem + sb +        offJ[e]) = (_Float16)pv0[e];           \
        *(_Float16*)(smem + sb + 4608 + offJ[e]) = (_Float16)pv1[e];           \
        *(_Float16*)(smem + sb + 9216 + offJ[e]) = (_Float16)pv2[e];           \
    }                                                                          \
    if (edgeAct) {                                                             \
        *(_Float16*)(smem + sb + offE1) = (_Float16)pe;                        \
        *(_Float16*)(smem + sb + offE0) = (_Float16)0.f;                       \
    }                                                                          \
} while (0)

__global__ __launch_bounds__(512)
__attribute__((amdgpu_waves_per_eu(4, 4)))
void caps_kernel(
    const float* __restrict__ x,      // (2,8,16,32,32,32) f32
    const _Float16* __restrict__ whB, // (14,4,128,8) f16
    const float* __restrict__ cb,     // (128,)
    const float* __restrict__ bias,   // (8,16)
    float* __restrict__ out)          // (2,8,16,32,32,32) f32
{
    __shared__ half8 smemv[4944];     // 79104 B = ring 41472 + zero 4608 + votes 33024
    char* smem = (char*)smemv;
    _Float16* Vh = (_Float16*)(smem + 46080);
    float* RT = (float*)(smem + 46080);          // overlays votes after B3
    float* LG = (float*)(smem + 46080) + 1152;

    const int t    = threadIdx.x;     // 0..511
    const int gid  = blockIdx.x;      // 512
    const int wseg = gid & 1;
    const int h    = (gid >> 1) & 31;
    const int dg   = (gid >> 6) & 3;
    const int b    = (gid >> 8) & 1;
    const int w0g  = wseg << 4;
    const int d0   = dg << 3;

    const float* xb = x + (size_t)b * 4194304;

    // ---- staging geometry: thread handles (ch = t>>2, seg = t&3) at dy = 0,1,2 ----
    const int ch  = t >> 2;
    const int seg = t & 3;
    const bool yv0 = (h >= 1), yv1 = true, yv2 = (h <= 30);
    const int gBase = ch * 32768 + (h - 1) * 32 + w0g + seg * 4;  // float units
    int offJ[4];
    #pragma unroll
    for (int e = 0; e < 4; e++) {
        const int j = seg * 4 + 1 + e;           // 1..16
        offJ[e] = j * 256 + (((ch >> 3) ^ (j & 15)) << 4) + ((ch & 7) << 1);
    }
    // edge task: threads 0..383 -> (dyE = t>>7, chE = t&127)
    const bool edgeAct = (t < 384);
    const int dyE = (t >> 7) & 3, chE = t & 127;
    const int yE = h + dyE - 1;
    const bool yvE = edgeAct && ((unsigned)yE < 32u);
    const int wsc = (w0g == 0) ? 16 : 15;
    const int jsc = (w0g == 0) ? 17 : 0;
    const int jz  = (w0g == 0) ? 0 : 17;
    const int gBaseE = chE * 32768 + yE * 32 + wsc;
    const int offE1 = dyE * 4608 + jsc * 256 + (((chE >> 3) ^ (jsc & 15)) << 4)
                      + ((chE & 7) << 1);
    const int offE0 = dyE * 4608 + jz * 256 + (((chE >> 3) ^ (jz & 15)) << 4)
                      + ((chE & 7) << 1);

    f32x4 pv0, pv1, pv2;
    float pe;

    const int dm0 = d0 % 3;

    // ---- fill: planes z = d0-1, d0, d0+1 -> slots s3(dm0+2), dm0, s3(dm0+1) ----
    LOADPLANE(d0 - 1);  DUMPPLANE(s3(dm0 + 2));
    LOADPLANE(d0);      DUMPPLANE(dm0);
    LOADPLANE(d0 + 1);  DUMPPLANE(s3(dm0 + 1));
    for (int i2 = t; i2 < 1152; i2 += 512) ((float*)(smem + 41472))[i2] = 0.f;
    LOADPLANE(d0 + 2);                        // prefetch for d=0's dump
    __syncthreads();

    // ---- GEMM geometry ----
    const int wid = t >> 6, lane = t & 63;
    const int q = lane >> 4, r = lane & 15;
    const int wy = wid >> 2, wx = wid & 3;    // 2 M-groups x 4 N-groups
    const int qlow = q & 1, tphase = q >> 1;

    int geo[14];   // dz | dy<<2 | dx<<4 | pad<<6
    #pragma unroll
    for (int c = 0; c < 14; c++) {
        const int tap = 2 * c + tphase;
        const int dz = tap / 9, r9 = tap - dz * 9;
        const int dy = r9 / 3, dx = r9 - dy * 3;
        geo[c] = (tap >= 27) ? 64 : (dz | (dy << 2) | (dx << 4));
    }
    int uA[4];
    #pragma unroll
    for (int mt = 0; mt < 4; mt++) uA[mt] = (wy * 4 + mt) * 2 + qlow;
    const _Float16* bpt = whB + (q * 128 + wx * 32 + r) * 8;

    // ---- routing geometry (hoisted) ----
    const int p2 = t >> 2, qd = t & 3;
    const int vv = p2 & 15, oo = p2 >> 4;
    float cbv[2], bl[4];
    #pragma unroll
    for (int nt = 0; nt < 2; nt++) cbv[nt] = cb[wx * 32 + nt * 16 + r];
    #pragma unroll
    for (int a = 0; a < 4; a++) bl[a] = bias[oo * 16 + qd * 4 + a];

    int dmC = dm0;

    #pragma unroll 1
    for (int d = 0; d < 8; ++d) {
        // ================= GEMM d (reads ring slots, no barriers) ==============
        f32x4 acc[4][2];
        #pragma unroll
        for (int i = 0; i < 4; i++)
            #pragma unroll
            for (int j = 0; j < 2; j++) acc[i][j] = (f32x4)0.f;

        half8 bf[2][2];
        #pragma unroll
        for (int nt = 0; nt < 2; nt++) bf[0][nt] = *(const half8*)(bpt + nt * 128);

        #pragma unroll
        for (int c = 0; c < 14; c++) {
            const int cur = c & 1;
            if (c < 13) {
                #pragma unroll
                for (int nt = 0; nt < 2; nt++)
                    bf[cur ^ 1][nt] = *(const half8*)(bpt + (c + 1) * 4096 + nt * 128);
            }
            const int g = geo[c];
            int sx = dmC + (g & 3) + 2;
            sx = (sx >= 3) ? sx - 3 : sx;
            sx = (sx >= 3) ? sx - 3 : sx;
            int rb = sx * 13824 + ((g >> 2) & 3) * 4608;
            rb = (g & 64) ? 41472 : rb;
            const int jw = r + ((g >> 4) & 3);
            const int rowb = rb + jw * 256;
            const int js = jw & 15;
            half8 af[4];
            #pragma unroll
            for (int mt = 0; mt < 4; mt++)
                af[mt] = *(const half8*)(smem + rowb + ((uA[mt] ^ js) << 4));
            #pragma unroll
            for (int mt = 0; mt < 4; mt++)
                #pragma unroll
                for (int nt = 0; nt < 2; nt++)
                    acc[mt][nt] = __builtin_amdgcn_mfma_f32_16x16x32_f16(
                        af[mt], bf[cur][nt], acc[mt][nt], 0, 0, 0);
        }
        __syncthreads();   // B1: all slab reads for d done

        // ---- dump prefetched plane z = d0+d+2 into dead slot, prefetch next ----
        if (d < 7) DUMPPLANE(s3(dmC + 2));
        if (d < 6) LOADPLANE(d0 + d + 3);

        // ---- votes epilogue: acc + conv bias -> Vh[v][i][n] f16 ----
        #pragma unroll
        for (int mt = 0; mt < 4; mt++) {
            #pragma unroll
            for (int nt = 0; nt < 2; nt++) {
                const int n = wx * 32 + nt * 16 + r;
                #pragma unroll
                for (int reg = 0; reg < 4; reg++) {
                    const int v = q * 4 + reg;       // C/D row = q*4+reg (verified)
                    const int i = wy * 4 + mt;
                    Vh[v * 1032 + i * 128 + n] = (_Float16)(acc[mt][nt][reg] + cbv[nt]);
                }
            }
        }
        __syncthreads();   // B2: votes + dumped plane visible

        // ================= routing: 128 (v,o) pairs x 4 atom-quarters ==========
        float vf[8][4];
        #pragma unroll
        for (int i = 0; i < 8; i++) {
            const half4 hv = *(const half4*)&Vh[vv * 1032 + i * 128 + oo * 16 + qd * 4];
            #pragma unroll
            for (int a = 0; a < 4; a++) vf[i][a] = (float)hv[a];
        }
        __syncthreads();   // B3: vote reads done -> RT/LG may overlay

        float vn[8];
        #pragma unroll
        for (int i = 0; i < 8; i++) {
            float s = 0.f;
            #pragma unroll
            for (int a = 0; a < 4; a++) s = fmaf(vf[i][a], vf[i][a], s);
            s += __shfl_xor(s, 1);
            s += __shfl_xor(s, 2);
            vn[i] = sqrtf(s);
        }

        float rt[8], pre[4];
        float lgr[8];
        #pragma unroll
        for (int i = 0; i < 8; i++) { rt[i] = 0.125f; lgr[i] = 0.f; }

        for (int it = 0; it < 3; it++) {
            #pragma unroll
            for (int a = 0; a < 4; a++) {
                float s = bl[a];
                #pragma unroll
                for (int i = 0; i < 8; i++) s = fmaf(rt[i], vf[i][a], s);
                pre[a] = s;
            }
            if (it == 2) break;

            float s2 = 0.f;
            #pragma unroll
            for (int a = 0; a < 4; a++) s2 = fmaf(pre[a], pre[a], s2);
            s2 += __shfl_xor(s2, 1);
            s2 += __shfl_xor(s2, 2);
            const float pn = sqrtf(s2);

            #pragma unroll
            for (int i = 0; i < 8; i++) {
                float dp = 0.f;
                #pragma unroll
                for (int a = 0; a < 4; a++) dp = fmaf(pre[a], vf[i][a], dp);
                dp += __shfl_xor(dp, 1);
                dp += __shfl_xor(dp, 2);
                lgr[i] += dp / fmaxf(pn * vn[i], 1e-8f);
            }
            if (qd == 0) {
                #pragma unroll
                for (int i = 0; i < 8; i++) LG[vv * 72 + i * 8 + oo] = lgr[i];
            }
            __syncthreads();

            {
                float ex[2], ps = 0.f;
                #pragma unroll
                for (int k = 0; k < 2; k++) {
                    ex[k] = __expf(LG[vv * 72 + oo * 8 + qd * 2 + k]);
                    ps += ex[k];
                }
                ps += __shfl_xor(ps, 1);
                ps += __shfl_xor(ps, 2);
                const float rs = 1.f / ps;
                #pragma unroll
                for (int k = 0; k < 2; k++)
                    RT[vv * 72 + oo * 8 + qd * 2 + k] = ex[k] * rs;
            }
            __syncthreads();

            #pragma unroll
            for (int i = 0; i < 8; i++) rt[i] = RT[vv * 72 + i * 8 + oo];
        }

        // ---- squash + store ----
        float s2 = 0.f;
        #pragma unroll
        for (int a = 0; a < 4; a++) s2 = fmaf(pre[a], pre[a], s2);
        s2 += __shfl_xor(s2, 1);
        s2 += __shfl_xor(s2, 2);
        const float nn = sqrtf(s2);
        const float scale = (s2 / (1.f + s2)) / (nn + 1e-12f);
        const size_t sp = (size_t)(d0 + d) * 1024 + h * 32 + w0g + vv;
        #pragma unroll
        for (int a = 0; a < 4; a++)
            out[((size_t)((b * 8 + oo) * 16 + qd * 4 + a)) * 32768 + sp] = pre[a] * scale;

        dmC = (dmC == 2) ? 0 : dmC + 1;
    }
}

extern "C" void kernel_launch(void* const* d_in, const int* in_sizes, int n_in,
                              void* d_out, int out_size, void* d_ws, size_t ws_size,
                              hipStream_t stream) {
    const float* x    = (const float*)d_in[0];
    const float* cw   = (const float*)d_in[1];
    const float* cb   = (const float*)d_in[2];
    const float* bias = (const float*)d_in[3];
    float* out = (float*)d_out;
    _Float16* whB = (_Float16*)d_ws;   // 57344 * 2 = 114688 B

    hipLaunchKernelGGL(prep_weights, dim3(224), dim3(256), 0, stream, cw, whB);
    hipLaunchKernelGGL(caps_kernel, dim3(512), dim3(512), 0, stream,
                       x, whB, cb, bias, out);
}